// Round 4
// baseline (403.697 us; speedup 1.0000x reference)
//
#include <hip/hip_runtime.h>
#include <cstdint>
#include <cstddef>

// ---------------------------------------------------------------------------
// RecurrentCrossAttentionLayer (linear attention, ELU feature map)
// B=4, L=2048, D_MODEL=1024, H=16, HD=64.
// Pipeline: convert->bf16; QKV proj GEMMs (MFMA, fused featuremap epilogue);
// S=V^T K + Z=sum K (VALU); O=Q S^T (+denom col) MFMA; final GEMM Wo.
// ---------------------------------------------------------------------------

typedef __attribute__((ext_vector_type(8))) short short8;
typedef __attribute__((ext_vector_type(4))) float f32x4;

#define EPS_F 1e-6f

__device__ __forceinline__ float bf2f(short u) {
  union { unsigned int i; float f; } c;
  c.i = ((unsigned int)(unsigned short)u) << 16;
  return c.f;
}
__device__ __forceinline__ unsigned short f2bf(float f) {
  union { float f; unsigned int i; } c;
  c.f = f;
  return (unsigned short)((c.i + 0x7fffu + ((c.i >> 16) & 1u)) >> 16);
}

typedef __attribute__((address_space(1))) const unsigned int gu32;
typedef __attribute__((address_space(3))) unsigned int lu32;

__device__ __forceinline__ void gload_lds16(const void* g, void* l) {
  __builtin_amdgcn_global_load_lds((gu32*)g, (lu32*)l, 16, 0, 0);
}

// ---------------------------------------------------------------------------
// 128x128 bf16 NT GEMM mainloop, K=1024, BK=64, 4 waves (64x64 quadrant each).
// LDS rows are 128B (64 bf16). XOR swizzle: LDS slot s of row r holds global
// 16B chunk (s ^ (r&7)); reader XORs the same way (involution, rule #21).
// ---------------------------------------------------------------------------
__device__ __forceinline__ void gemm_mainloop(const char* Ab, const char* Bb,
                                              char* AsB, char* BsB,
                                              int tm, int tn, f32x4 acc[4][4]) {
  const int t = threadIdx.x;
  const int l = t & 63;
  const int w = t >> 6;
  const int srow = l >> 3, sslot = l & 7;
  const int sso16 = ((sslot ^ srow) << 4);        // pre-swizzled source chunk
  const int rd0 = ((l & 15) << 7) | ((((l >> 4) + 0) ^ (l & 7)) << 4);
  const int rd1 = ((l & 15) << 7) | ((((l >> 4) + 4) ^ (l & 7)) << 4);
  const int wr = (w >> 1) << 6;
  const int wc = (w & 1) << 6;

#pragma unroll
  for (int i = 0; i < 4; ++i)
#pragma unroll
    for (int j = 0; j < 4; ++j) acc[i][j] = f32x4{0.f, 0.f, 0.f, 0.f};

  const char* Ag = Ab + (size_t)tm * 2048;  // row stride = 1024*2B
  const char* Bg = Bb + (size_t)tn * 2048;

  for (int kt = 0; kt < 16; ++kt) {
    __syncthreads();  // protect LDS from overwrite
    const int kofs = kt << 7;  // 64 bf16 = 128B per K-tile
#pragma unroll
    for (int i = 0; i < 4; ++i) {
      const int rr = (((w << 2) + i) << 3) + srow;  // 0..127
      gload_lds16(Ag + (size_t)rr * 2048 + kofs + sso16,
                  AsB + rr * 128 + (sslot << 4));
      gload_lds16(Bg + (size_t)rr * 2048 + kofs + sso16,
                  BsB + rr * 128 + (sslot << 4));
    }
    __syncthreads();  // compiler drains vmcnt(0) here
#pragma unroll
    for (int kk = 0; kk < 2; ++kk) {
      const int rdo = kk ? rd1 : rd0;
      short8 a[4], b[4];
#pragma unroll
      for (int i = 0; i < 4; ++i)
        a[i] = *(const short8*)(AsB + ((wr + i * 16) << 7) + rdo);
#pragma unroll
      for (int j = 0; j < 4; ++j)
        b[j] = *(const short8*)(BsB + ((wc + j * 16) << 7) + rdo);
#pragma unroll
      for (int i = 0; i < 4; ++i)
#pragma unroll
        for (int j = 0; j < 4; ++j)
          acc[i][j] = __builtin_amdgcn_mfma_f32_16x16x32_bf16(a[i], b[j],
                                                              acc[i][j], 0, 0, 0);
    }
  }
}

// ---------------------------------------------------------------------------
// QKV projection GEMMs (blockIdx.z = 0/1/2 -> q/k/v), fused feature-map
// epilogue, head-split output [B*H, L, 64] bf16.
// ---------------------------------------------------------------------------
__global__ __launch_bounds__(256) void proj_gemm(
    const short* __restrict__ qb, const short* __restrict__ kb,
    const short* __restrict__ vb, const short* __restrict__ Wq,
    const short* __restrict__ Wk, const short* __restrict__ Wv,
    const float* __restrict__ bq, const float* __restrict__ bk,
    const float* __restrict__ bv, unsigned short* __restrict__ Qf,
    unsigned short* __restrict__ Kf, unsigned short* __restrict__ Vf,
    const unsigned char* __restrict__ mask) {
  __shared__ char As[16384], Bs[16384];
  const int mode = blockIdx.z;
  const short* A = mode == 0 ? qb : (mode == 1 ? kb : vb);
  const short* B = mode == 0 ? Wq : (mode == 1 ? Wk : Wv);
  const float* bias = mode == 0 ? bq : (mode == 1 ? bk : bv);
  unsigned short* O = mode == 0 ? Qf : (mode == 1 ? Kf : Vf);
  const int tm = blockIdx.x << 7, tn = blockIdx.y << 7;
  f32x4 acc[4][4];
  gemm_mainloop((const char*)A, (const char*)B, As, Bs, tm, tn, acc);

  const int l = threadIdx.x & 63, w = threadIdx.x >> 6;
  const int wr = (w >> 1) << 6, wc = (w & 1) << 6;
  const int lr = (l >> 4) << 2, lc = l & 15;
#pragma unroll
  for (int i = 0; i < 4; ++i) {
#pragma unroll
    for (int r = 0; r < 4; ++r) {
      const int row = tm + wr + i * 16 + lr + r;  // 0..8191 = b*2048+s
      const bool msk = (mode == 1) && (mask[row] != 0);
      const int b = row >> 11, s = row & 2047;
#pragma unroll
      for (int j = 0; j < 4; ++j) {
        const int col = tn + wc + j * 16 + lc;  // 0..1023 = h*64+d
        float v = acc[i][j][r] + bias[col];
        if (mode == 0) {
          v *= 0.125f;                       // HEAD_DIM^-0.5
          v = (v > 0.f) ? (v + 1.f) : __expf(v);  // elu+1
        } else if (mode == 1) {
          v = (v > 0.f) ? (v + 1.f) : __expf(v);
          if (msk) v = 0.f;
        }
        const int h = col >> 6, d = col & 63;
        O[((size_t)(b * 16 + h) * 2048 + s) * 64 + d] = f2bf(v);
      }
    }
  }
}

// ---------------------------------------------------------------------------
// Final GEMM: out = out2 @ Wo^T + bo, fp32 output.
// ---------------------------------------------------------------------------
__global__ __launch_bounds__(256) void final_gemm(const short* __restrict__ A,
                                                  const short* __restrict__ Wo,
                                                  const float* __restrict__ bo,
                                                  float* __restrict__ out) {
  __shared__ char As[16384], Bs[16384];
  const int tm = blockIdx.x << 7, tn = blockIdx.y << 7;
  f32x4 acc[4][4];
  gemm_mainloop((const char*)A, (const char*)Wo, As, Bs, tm, tn, acc);
  const int l = threadIdx.x & 63, w = threadIdx.x >> 6;
  const int wr = (w >> 1) << 6, wc = (w & 1) << 6;
  const int lr = (l >> 4) << 2, lc = l & 15;
#pragma unroll
  for (int i = 0; i < 4; ++i)
#pragma unroll
    for (int r = 0; r < 4; ++r) {
      const int row = tm + wr + i * 16 + lr + r;
#pragma unroll
      for (int j = 0; j < 4; ++j) {
        const int col = tn + wc + j * 16 + lc;
        out[(size_t)row * 1024 + col] = acc[i][j][r] + bo[col];
      }
    }
}

// ---------------------------------------------------------------------------
// S partials: per (bh, chunk of 256 s): S[m][d] += V[s][m]*K[s][d] (fp32 VALU).
// part[chunk][bh][4096]
// ---------------------------------------------------------------------------
__global__ __launch_bounds__(256) void s_partial(
    const unsigned short* __restrict__ Kf, const unsigned short* __restrict__ Vf,
    float* __restrict__ part) {
  __shared__ float sh[8192];  // K:0..4095, V:4096..8191; later Sred [64][65]
  const int bh = blockIdx.x, ch = blockIdx.y;
  const int t = threadIdx.x, m = t & 63, w = t >> 6;
  const size_t base = ((size_t)bh * 2048 + ch * 256) * 64;
  const unsigned short* Kb = Kf + base;
  const unsigned short* Vb = Vf + base;
  float acc[64];
#pragma unroll
  for (int d = 0; d < 64; ++d) acc[d] = 0.f;

  for (int st = 0; st < 4; ++st) {
    __syncthreads();
    const int o = st * 4096;
#pragma unroll
    for (int e = 0; e < 16; ++e) {
      const int idx = e * 256 + t;  // coalesced loads, conflict-free LDS writes
      sh[idx] = bf2f((short)Kb[o + idx]);
      sh[4096 + idx] = bf2f((short)Vb[o + idx]);
    }
    __syncthreads();
    const int s0 = w << 4;
    for (int s = s0; s < s0 + 16; ++s) {
      const float v = sh[4096 + s * 64 + m];
      const f32x4* kr = (const f32x4*)&sh[s * 64];  // broadcast reads
#pragma unroll
      for (int db = 0; db < 16; ++db) {
        const f32x4 kq = kr[db];
        acc[db * 4 + 0] += v * kq[0];
        acc[db * 4 + 1] += v * kq[1];
        acc[db * 4 + 2] += v * kq[2];
        acc[db * 4 + 3] += v * kq[3];
      }
    }
  }
  __syncthreads();
  // cross-wave reduce into padded LDS [64][65]
  for (int wv = 0; wv < 4; ++wv) {
    if (w == wv) {
#pragma unroll
      for (int d = 0; d < 64; ++d) {
        if (wv == 0) sh[m * 65 + d] = acc[d];
        else         sh[m * 65 + d] += acc[d];
      }
    }
    __syncthreads();
  }
  float* po = part + ((size_t)ch * 64 + bh) * 4096;
#pragma unroll
  for (int i = 0; i < 16; ++i) {
    const int idx = i * 256 + t;
    po[idx] = sh[(idx >> 6) * 65 + (idx & 63)];
  }
}

// ---------------------------------------------------------------------------
// Reduce partials -> S_ext bf16 [bh][80][64]: rows 0..63 = S, row 64 = Z,
// rows 65..79 = 0 (MFMA N-padding).
// ---------------------------------------------------------------------------
__global__ __launch_bounds__(256) void s_reduce(const float* __restrict__ part,
                                                const unsigned short* __restrict__ Kf,
                                                unsigned short* __restrict__ Sext) {
  const int bh = blockIdx.x, t = threadIdx.x;
  unsigned short* So = Sext + (size_t)bh * 5120;
#pragma unroll
  for (int i = 0; i < 16; ++i) {
    const int idx = i * 256 + t;
    float a = 0.f;
#pragma unroll
    for (int c = 0; c < 8; ++c) a += part[((size_t)c * 64 + bh) * 4096 + idx];
    So[idx] = f2bf(a);
  }
  // Z = sum_s K[s][d]
  const unsigned short* kp = Kf + (size_t)bh * 2048 * 64;
  float z = 0.f;
  for (int s = (t >> 6); s < 2048; s += 4) z += bf2f((short)kp[s * 64 + (t & 63)]);
  __shared__ float zs[256];
  zs[t] = z;
  __syncthreads();
  if (t < 64) So[4096 + t] = f2bf(zs[t] + zs[64 + t] + zs[128 + t] + zs[192 + t]);
  for (int i = t; i < 960; i += 256) So[4160 + i] = 0;
}

// ---------------------------------------------------------------------------
// O = Q @ S_ext^T per (bh, 128-row q tile); col 64 = denominator Q.Z.
// Writes normalized out2 bf16 [B, L, 1024].
// ---------------------------------------------------------------------------
__global__ __launch_bounds__(256) void out_gemm(const unsigned short* __restrict__ Qf,
                                                const unsigned short* __restrict__ Sext,
                                                unsigned short* __restrict__ out2) {
  __shared__ char Qs[16384], Ss[10240];
  const int qt = blockIdx.x, bh = blockIdx.y;
  const int t = threadIdx.x, l = t & 63, w = t >> 6;
  const int srow = l >> 3, sslot = l & 7;
  const int sso16 = ((sslot ^ srow) << 4);
  const char* Qg = (const char*)(Qf + ((size_t)bh * 2048 + qt * 128) * 64);
  const char* Sg = (const char*)(Sext + (size_t)bh * 5120);
  for (int i = w; i < 16; i += 4) {
    const int rr = (i << 3) + srow;
    gload_lds16(Qg + (size_t)rr * 128 + sso16, Qs + rr * 128 + (sslot << 4));
  }
  for (int i = w; i < 10; i += 4) {
    const int rr = (i << 3) + srow;
    gload_lds16(Sg + (size_t)rr * 128 + sso16, Ss + rr * 128 + (sslot << 4));
  }
  __syncthreads();
  const int rd0 = ((l & 15) << 7) | ((((l >> 4) + 0) ^ (l & 7)) << 4);
  const int rd1 = ((l & 15) << 7) | ((((l >> 4) + 4) ^ (l & 7)) << 4);
  f32x4 acc[2][5];
#pragma unroll
  for (int i = 0; i < 2; ++i)
#pragma unroll
    for (int j = 0; j < 5; ++j) acc[i][j] = f32x4{0.f, 0.f, 0.f, 0.f};
#pragma unroll
  for (int kk = 0; kk < 2; ++kk) {
    const int rdo = kk ? rd1 : rd0;
    short8 a[2], b[5];
#pragma unroll
    for (int i = 0; i < 2; ++i)
      a[i] = *(const short8*)(Qs + ((w * 32 + i * 16) << 7) + rdo);
#pragma unroll
    for (int j = 0; j < 5; ++j)
      b[j] = *(const short8*)(Ss + ((j * 16) << 7) + rdo);
#pragma unroll
    for (int i = 0; i < 2; ++i)
#pragma unroll
      for (int j = 0; j < 5; ++j)
        acc[i][j] = __builtin_amdgcn_mfma_f32_16x16x32_bf16(a[i], b[j],
                                                            acc[i][j], 0, 0, 0);
  }
  const int b_ = bh >> 4, h = bh & 15;
#pragma unroll
  for (int i = 0; i < 2; ++i) {
#pragma unroll
    for (int r = 0; r < 4; ++r) {
      const float dv = __shfl(acc[i][4][r], (l & 48));  // col 64 holder
      const float qz = 1.f / (dv + EPS_F);
      const int q = qt * 128 + w * 32 + i * 16 + ((l >> 4) << 2) + r;
      unsigned short* po = out2 + ((size_t)b_ * 2048 + q) * 1024 + h * 64;
#pragma unroll
      for (int j = 0; j < 4; ++j) po[j * 16 + (l & 15)] = f2bf(acc[i][j][r] * qz);
    }
  }
}

// ---------------------------------------------------------------------------
// fp32 -> bf16 conversion for 3 big inputs + 4 weight matrices.
// ---------------------------------------------------------------------------
__global__ __launch_bounds__(256) void convert_all(
    const float* __restrict__ s0, const float* __restrict__ s1,
    const float* __restrict__ s2, const float* __restrict__ s3,
    const float* __restrict__ s4, const float* __restrict__ s5,
    const float* __restrict__ s6, unsigned short* __restrict__ d0,
    unsigned short* __restrict__ d1, unsigned short* __restrict__ d2,
    unsigned short* __restrict__ d3, unsigned short* __restrict__ d4,
    unsigned short* __restrict__ d5, unsigned short* __restrict__ d6) {
  const int seg = blockIdx.y;
  const float* src;
  unsigned short* dst;
  int n;
  switch (seg) {
    case 0: src = s0; dst = d0; n = 8388608; break;
    case 1: src = s1; dst = d1; n = 8388608; break;
    case 2: src = s2; dst = d2; n = 8388608; break;
    case 3: src = s3; dst = d3; n = 1048576; break;
    case 4: src = s4; dst = d4; n = 1048576; break;
    case 5: src = s5; dst = d5; n = 1048576; break;
    default: src = s6; dst = d6; n = 1048576; break;
  }
  const int idx = (blockIdx.x * 256 + threadIdx.x) * 8;
  if (idx >= n) return;
  const f32x4 a = *(const f32x4*)(src + idx);
  const f32x4 b = *(const f32x4*)(src + idx + 4);
  union { unsigned short u[8]; short8 v; } o;
#pragma unroll
  for (int e = 0; e < 4; ++e) {
    o.u[e] = f2bf(a[e]);
    o.u[4 + e] = f2bf(b[e]);
  }
  *(short8*)(dst + idx) = o.v;
}

// ---------------------------------------------------------------------------
extern "C" void kernel_launch(void* const* d_in, const int* in_sizes, int n_in,
                              void* d_out, int out_size, void* d_ws,
                              size_t ws_size, hipStream_t stream) {
  const float* querys = (const float*)d_in[0];
  const float* keys = (const float*)d_in[1];
  const float* values = (const float*)d_in[2];
  const unsigned char* mask = (const unsigned char*)d_in[3];
  const float* Wq = (const float*)d_in[4];
  const float* bq = (const float*)d_in[5];
  const float* Wk = (const float*)d_in[6];
  const float* bk = (const float*)d_in[7];
  const float* Wv = (const float*)d_in[8];
  const float* bv = (const float*)d_in[9];
  const float* Wo = (const float*)d_in[10];
  const float* bo = (const float*)d_in[11];
  float* out = (float*)d_out;

  char* ws = (char*)d_ws;
  unsigned short* qb  = (unsigned short*)(ws + 0);          // 16 MB
  unsigned short* kb  = (unsigned short*)(ws + 16777216);   // 16 MB
  unsigned short* vb  = (unsigned short*)(ws + 33554432);   // 16 MB
  unsigned short* wqb = (unsigned short*)(ws + 50331648);   // 2 MB
  unsigned short* wkb = (unsigned short*)(ws + 52428800);   // 2 MB
  unsigned short* wvb = (unsigned short*)(ws + 54525952);   // 2 MB
  unsigned short* wob = (unsigned short*)(ws + 56623104);   // 2 MB
  unsigned short* Qf  = (unsigned short*)(ws + 58720256);   // 16 MB
  unsigned short* Kf  = (unsigned short*)(ws + 75497472);   // 16 MB
  unsigned short* Vf  = (unsigned short*)(ws + 92274688);   // 16 MB
  float* part         = (float*)(ws + 109051904);           // 8.39 MB
  unsigned short* Sx  = (unsigned short*)(ws + 117440512);  // 0.66 MB
  unsigned short* out2 = qb;  // qb dead after proj_gemm; reuse as out2

  convert_all<<<dim3(4096, 7), 256, 0, stream>>>(querys, keys, values, Wq, Wk,
                                                 Wv, Wo, qb, kb, vb, wqb, wkb,
                                                 wvb, wob);
  proj_gemm<<<dim3(64, 8, 3), 256, 0, stream>>>(
      (const short*)qb, (const short*)kb, (const short*)vb, (const short*)wqb,
      (const short*)wkb, (const short*)wvb, bq, bk, bv, Qf, Kf, Vf, mask);
  s_partial<<<dim3(64, 8), 256, 0, stream>>>(Kf, Vf, part);
  s_reduce<<<dim3(64), 256, 0, stream>>>(part, Kf, Sx);
  out_gemm<<<dim3(16, 64), 256, 0, stream>>>(Qf, Sx, out2);
  final_gemm<<<dim3(64, 8), 256, 0, stream>>>((const short*)out2,
                                              (const short*)wob, bo, out);
}

// Round 6
// 300.597 us; speedup vs baseline: 1.3430x; 1.3430x over previous
//
#include <hip/hip_runtime.h>
#include <cstdint>
#include <cstddef>

// ---------------------------------------------------------------------------
// RecurrentCrossAttentionLayer (linear attention, ELU feature map)
// B=4, L=2048, D_MODEL=1024, H=16, HD=64.
// Pipeline: convert->bf16; QKV proj GEMMs (MFMA, fused featuremap epilogue);
// S=V^T K + Z=sum K partials (VALU, fused); coalesced reduce; O=Q S^T MFMA;
// final GEMM Wo.
// R4 change: Z folded into s_partial (was a 512-stride-load/thread serial loop
// in s_reduce at 2.6% occupancy = 130us); s_reduce now coalesced, grid x4.
// ---------------------------------------------------------------------------

typedef __attribute__((ext_vector_type(8))) short short8;
typedef __attribute__((ext_vector_type(4))) float f32x4;

#define EPS_F 1e-6f

__device__ __forceinline__ float bf2f(short u) {
  union { unsigned int i; float f; } c;
  c.i = ((unsigned int)(unsigned short)u) << 16;
  return c.f;
}
__device__ __forceinline__ unsigned short f2bf(float f) {
  union { float f; unsigned int i; } c;
  c.f = f;
  return (unsigned short)((c.i + 0x7fffu + ((c.i >> 16) & 1u)) >> 16);
}

typedef __attribute__((address_space(1))) const unsigned int gu32;
typedef __attribute__((address_space(3))) unsigned int lu32;

__device__ __forceinline__ void gload_lds16(const void* g, void* l) {
  __builtin_amdgcn_global_load_lds((gu32*)g, (lu32*)l, 16, 0, 0);
}

// ---------------------------------------------------------------------------
// 128x128 bf16 NT GEMM mainloop, K=1024, BK=64, 4 waves (64x64 quadrant each).
// LDS rows are 128B (64 bf16). XOR swizzle: LDS slot s of row r holds global
// 16B chunk (s ^ (r&7)); reader XORs the same way (involution, rule #21).
// ---------------------------------------------------------------------------
__device__ __forceinline__ void gemm_mainloop(const char* Ab, const char* Bb,
                                              char* AsB, char* BsB,
                                              int tm, int tn, f32x4 acc[4][4]) {
  const int t = threadIdx.x;
  const int l = t & 63;
  const int w = t >> 6;
  const int srow = l >> 3, sslot = l & 7;
  const int sso16 = ((sslot ^ srow) << 4);        // pre-swizzled source chunk
  const int rd0 = ((l & 15) << 7) | ((((l >> 4) + 0) ^ (l & 7)) << 4);
  const int rd1 = ((l & 15) << 7) | ((((l >> 4) + 4) ^ (l & 7)) << 4);
  const int wr = (w >> 1) << 6;
  const int wc = (w & 1) << 6;

#pragma unroll
  for (int i = 0; i < 4; ++i)
#pragma unroll
    for (int j = 0; j < 4; ++j) acc[i][j] = f32x4{0.f, 0.f, 0.f, 0.f};

  const char* Ag = Ab + (size_t)tm * 2048;  // row stride = 1024*2B
  const char* Bg = Bb + (size_t)tn * 2048;

  for (int kt = 0; kt < 16; ++kt) {
    __syncthreads();  // protect LDS from overwrite
    const int kofs = kt << 7;  // 64 bf16 = 128B per K-tile
#pragma unroll
    for (int i = 0; i < 4; ++i) {
      const int rr = (((w << 2) + i) << 3) + srow;  // 0..127
      gload_lds16(Ag + (size_t)rr * 2048 + kofs + sso16,
                  AsB + rr * 128 + (sslot << 4));
      gload_lds16(Bg + (size_t)rr * 2048 + kofs + sso16,
                  BsB + rr * 128 + (sslot << 4));
    }
    __syncthreads();  // compiler drains vmcnt(0) here
#pragma unroll
    for (int kk = 0; kk < 2; ++kk) {
      const int rdo = kk ? rd1 : rd0;
      short8 a[4], b[4];
#pragma unroll
      for (int i = 0; i < 4; ++i)
        a[i] = *(const short8*)(AsB + ((wr + i * 16) << 7) + rdo);
#pragma unroll
      for (int j = 0; j < 4; ++j)
        b[j] = *(const short8*)(BsB + ((wc + j * 16) << 7) + rdo);
#pragma unroll
      for (int i = 0; i < 4; ++i)
#pragma unroll
        for (int j = 0; j < 4; ++j)
          acc[i][j] = __builtin_amdgcn_mfma_f32_16x16x32_bf16(a[i], b[j],
                                                              acc[i][j], 0, 0, 0);
    }
  }
}

// ---------------------------------------------------------------------------
// QKV projection GEMMs (blockIdx.z = 0/1/2 -> q/k/v), fused feature-map
// epilogue, head-split output [B*H, L, 64] bf16.
// ---------------------------------------------------------------------------
__global__ __launch_bounds__(256) void proj_gemm(
    const short* __restrict__ qb, const short* __restrict__ kb,
    const short* __restrict__ vb, const short* __restrict__ Wq,
    const short* __restrict__ Wk, const short* __restrict__ Wv,
    const float* __restrict__ bq, const float* __restrict__ bk,
    const float* __restrict__ bv, unsigned short* __restrict__ Qf,
    unsigned short* __restrict__ Kf, unsigned short* __restrict__ Vf,
    const unsigned char* __restrict__ mask) {
  __shared__ char As[16384], Bs[16384];
  const int mode = blockIdx.z;
  const short* A = mode == 0 ? qb : (mode == 1 ? kb : vb);
  const short* B = mode == 0 ? Wq : (mode == 1 ? Wk : Wv);
  const float* bias = mode == 0 ? bq : (mode == 1 ? bk : bv);
  unsigned short* O = mode == 0 ? Qf : (mode == 1 ? Kf : Vf);
  const int tm = blockIdx.x << 7, tn = blockIdx.y << 7;
  f32x4 acc[4][4];
  gemm_mainloop((const char*)A, (const char*)B, As, Bs, tm, tn, acc);

  const int l = threadIdx.x & 63, w = threadIdx.x >> 6;
  const int wr = (w >> 1) << 6, wc = (w & 1) << 6;
  const int lr = (l >> 4) << 2, lc = l & 15;
#pragma unroll
  for (int i = 0; i < 4; ++i) {
#pragma unroll
    for (int r = 0; r < 4; ++r) {
      const int row = tm + wr + i * 16 + lr + r;  // 0..8191 = b*2048+s
      const bool msk = (mode == 1) && (mask[row] != 0);
      const int b = row >> 11, s = row & 2047;
#pragma unroll
      for (int j = 0; j < 4; ++j) {
        const int col = tn + wc + j * 16 + lc;  // 0..1023 = h*64+d
        float v = acc[i][j][r] + bias[col];
        if (mode == 0) {
          v *= 0.125f;                       // HEAD_DIM^-0.5
          v = (v > 0.f) ? (v + 1.f) : __expf(v);  // elu+1
        } else if (mode == 1) {
          v = (v > 0.f) ? (v + 1.f) : __expf(v);
          if (msk) v = 0.f;
        }
        const int h = col >> 6, d = col & 63;
        O[((size_t)(b * 16 + h) * 2048 + s) * 64 + d] = f2bf(v);
      }
    }
  }
}

// ---------------------------------------------------------------------------
// Final GEMM: out = out2 @ Wo^T + bo, fp32 output.
// ---------------------------------------------------------------------------
__global__ __launch_bounds__(256) void final_gemm(const short* __restrict__ A,
                                                  const short* __restrict__ Wo,
                                                  const float* __restrict__ bo,
                                                  float* __restrict__ out) {
  __shared__ char As[16384], Bs[16384];
  const int tm = blockIdx.x << 7, tn = blockIdx.y << 7;
  f32x4 acc[4][4];
  gemm_mainloop((const char*)A, (const char*)Wo, As, Bs, tm, tn, acc);
  const int l = threadIdx.x & 63, w = threadIdx.x >> 6;
  const int wr = (w >> 1) << 6, wc = (w & 1) << 6;
  const int lr = (l >> 4) << 2, lc = l & 15;
#pragma unroll
  for (int i = 0; i < 4; ++i)
#pragma unroll
    for (int r = 0; r < 4; ++r) {
      const int row = tm + wr + i * 16 + lr + r;
#pragma unroll
      for (int j = 0; j < 4; ++j) {
        const int col = tn + wc + j * 16 + lc;
        out[(size_t)row * 1024 + col] = acc[i][j][r] + bo[col];
      }
    }
}

// ---------------------------------------------------------------------------
// S+Z partials per (bh, chunk of 256 s):
//   S[m][d] += V[s][m]*K[s][d]  (fp32 VALU)
//   Z[d]    += K[s][d]          (from the same LDS-staged K)
// part row = [4096 S | 64 Z], stride 4160 floats.
// ---------------------------------------------------------------------------
__global__ __launch_bounds__(256) void s_partial(
    const unsigned short* __restrict__ Kf, const unsigned short* __restrict__ Vf,
    float* __restrict__ part) {
  __shared__ float sh[8192];  // K:0..4095, V:4096..8191; later Sred[64][65]+Z
  const int bh = blockIdx.x, ch = blockIdx.y;
  const int t = threadIdx.x, m = t & 63, w = t >> 6;
  const size_t base = ((size_t)bh * 2048 + ch * 256) * 64;
  const unsigned short* Kb = Kf + base;
  const unsigned short* Vb = Vf + base;
  float acc[64];
#pragma unroll
  for (int d = 0; d < 64; ++d) acc[d] = 0.f;
  float z = 0.f;  // partial Z for d = t&63, s-subset (w*16..w*16+16) per chunk

  for (int st = 0; st < 4; ++st) {
    __syncthreads();
    const int o = st * 4096;
#pragma unroll
    for (int e = 0; e < 16; ++e) {
      const int idx = e * 256 + t;  // coalesced loads, conflict-free LDS writes
      sh[idx] = bf2f((short)Kb[o + idx]);
      sh[4096 + idx] = bf2f((short)Vb[o + idx]);
    }
    __syncthreads();
    const int s0 = w << 4;
    for (int s = s0; s < s0 + 16; ++s) {
      const float v = sh[4096 + s * 64 + m];
      const f32x4* kr = (const f32x4*)&sh[s * 64];  // broadcast reads
      z += sh[s * 64 + m];                          // stride-1 across lanes
#pragma unroll
      for (int db = 0; db < 16; ++db) {
        const f32x4 kq = kr[db];
        acc[db * 4 + 0] += v * kq[0];
        acc[db * 4 + 1] += v * kq[1];
        acc[db * 4 + 2] += v * kq[2];
        acc[db * 4 + 3] += v * kq[3];
      }
    }
  }
  __syncthreads();
  sh[4160 + t] = z;  // disjoint from Sred region [0,4160)
  // cross-wave reduce S into padded LDS [64][65]
  for (int wv = 0; wv < 4; ++wv) {
    if (w == wv) {
#pragma unroll
      for (int d = 0; d < 64; ++d) {
        if (wv == 0) sh[m * 65 + d] = acc[d];
        else         sh[m * 65 + d] += acc[d];
      }
    }
    __syncthreads();
  }
  float* po = part + ((size_t)ch * 64 + bh) * 4160;
#pragma unroll
  for (int i = 0; i < 16; ++i) {
    const int idx = i * 256 + t;
    po[idx] = sh[(idx >> 6) * 65 + (idx & 63)];
  }
  if (t < 64)
    po[4096 + t] = sh[4160 + t] + sh[4224 + t] + sh[4288 + t] + sh[4352 + t];
}

// ---------------------------------------------------------------------------
// Coalesced reduce of 8 chunk-partials -> S_ext bf16 [bh][80][64]:
// rows 0..63 = S, row 64 = Z, rows 65..79 = 0 (MFMA N-padding).
// grid (64 bh, 4 seg): each seg sums 1024 S elems; seg0 also Z, seg3 zeros pad.
// ---------------------------------------------------------------------------
__global__ __launch_bounds__(256) void s_reduce(const float* __restrict__ part,
                                                unsigned short* __restrict__ Sext) {
  const int bh = blockIdx.x, seg = blockIdx.y, t = threadIdx.x;
  unsigned short* So = Sext + (size_t)bh * 5120;
  const float* pb = part + (size_t)bh * 4160;
#pragma unroll
  for (int i = 0; i < 4; ++i) {
    const int idx = seg * 1024 + i * 256 + t;
    float a = 0.f;
#pragma unroll
    for (int c = 0; c < 8; ++c) a += pb[(size_t)c * 64 * 4160 + idx];
    So[idx] = f2bf(a);
  }
  if (seg == 0 && t < 64) {
    float a = 0.f;
#pragma unroll
    for (int c = 0; c < 8; ++c) a += pb[(size_t)c * 64 * 4160 + 4096 + t];
    So[4096 + t] = f2bf(a);
  }
  if (seg == 3)
    for (int i = t; i < 960; i += 256) So[4160 + i] = 0;
}

// ---------------------------------------------------------------------------
// O = Q @ S_ext^T per (bh, 128-row q tile); col 64 = denominator Q.Z.
// Writes normalized out2 bf16 [B, L, 1024].
// ---------------------------------------------------------------------------
__global__ __launch_bounds__(256) void out_gemm(const unsigned short* __restrict__ Qf,
                                                const unsigned short* __restrict__ Sext,
                                                unsigned short* __restrict__ out2) {
  __shared__ char Qs[16384], Ss[10240];
  const int qt = blockIdx.x, bh = blockIdx.y;
  const int t = threadIdx.x, l = t & 63, w = t >> 6;
  const int srow = l >> 3, sslot = l & 7;
  const int sso16 = ((sslot ^ srow) << 4);
  const char* Qg = (const char*)(Qf + ((size_t)bh * 2048 + qt * 128) * 64);
  const char* Sg = (const char*)(Sext + (size_t)bh * 5120);
  for (int i = w; i < 16; i += 4) {
    const int rr = (i << 3) + srow;
    gload_lds16(Qg + (size_t)rr * 128 + sso16, Qs + rr * 128 + (sslot << 4));
  }
  for (int i = w; i < 10; i += 4) {
    const int rr = (i << 3) + srow;
    gload_lds16(Sg + (size_t)rr * 128 + sso16, Ss + rr * 128 + (sslot << 4));
  }
  __syncthreads();
  const int rd0 = ((l & 15) << 7) | ((((l >> 4) + 0) ^ (l & 7)) << 4);
  const int rd1 = ((l & 15) << 7) | ((((l >> 4) + 4) ^ (l & 7)) << 4);
  f32x4 acc[2][5];
#pragma unroll
  for (int i = 0; i < 2; ++i)
#pragma unroll
    for (int j = 0; j < 5; ++j) acc[i][j] = f32x4{0.f, 0.f, 0.f, 0.f};
#pragma unroll
  for (int kk = 0; kk < 2; ++kk) {
    const int rdo = kk ? rd1 : rd0;
    short8 a[2], b[5];
#pragma unroll
    for (int i = 0; i < 2; ++i)
      a[i] = *(const short8*)(Qs + ((w * 32 + i * 16) << 7) + rdo);
#pragma unroll
    for (int j = 0; j < 5; ++j)
      b[j] = *(const short8*)(Ss + ((j * 16) << 7) + rdo);
#pragma unroll
    for (int i = 0; i < 2; ++i)
#pragma unroll
      for (int j = 0; j < 5; ++j)
        acc[i][j] = __builtin_amdgcn_mfma_f32_16x16x32_bf16(a[i], b[j],
                                                            acc[i][j], 0, 0, 0);
  }
  const int b_ = bh >> 4, h = bh & 15;
#pragma unroll
  for (int i = 0; i < 2; ++i) {
#pragma unroll
    for (int r = 0; r < 4; ++r) {
      const float dv = __shfl(acc[i][4][r], (l & 48));  // col 64 holder
      const float qz = 1.f / (dv + EPS_F);
      const int q = qt * 128 + w * 32 + i * 16 + ((l >> 4) << 2) + r;
      unsigned short* po = out2 + ((size_t)b_ * 2048 + q) * 1024 + h * 64;
#pragma unroll
      for (int j = 0; j < 4; ++j) po[j * 16 + (l & 15)] = f2bf(acc[i][j][r] * qz);
    }
  }
}

// ---------------------------------------------------------------------------
// fp32 -> bf16 conversion for 3 big inputs + 4 weight matrices.
// ---------------------------------------------------------------------------
__global__ __launch_bounds__(256) void convert_all(
    const float* __restrict__ s0, const float* __restrict__ s1,
    const float* __restrict__ s2, const float* __restrict__ s3,
    const float* __restrict__ s4, const float* __restrict__ s5,
    const float* __restrict__ s6, unsigned short* __restrict__ d0,
    unsigned short* __restrict__ d1, unsigned short* __restrict__ d2,
    unsigned short* __restrict__ d3, unsigned short* __restrict__ d4,
    unsigned short* __restrict__ d5, unsigned short* __restrict__ d6) {
  const int seg = blockIdx.y;
  const float* src;
  unsigned short* dst;
  int n;
  switch (seg) {
    case 0: src = s0; dst = d0; n = 8388608; break;
    case 1: src = s1; dst = d1; n = 8388608; break;
    case 2: src = s2; dst = d2; n = 8388608; break;
    case 3: src = s3; dst = d3; n = 1048576; break;
    case 4: src = s4; dst = d4; n = 1048576; break;
    case 5: src = s5; dst = d5; n = 1048576; break;
    default: src = s6; dst = d6; n = 1048576; break;
  }
  const int idx = (blockIdx.x * 256 + threadIdx.x) * 8;
  if (idx >= n) return;
  const f32x4 a = *(const f32x4*)(src + idx);
  const f32x4 b = *(const f32x4*)(src + idx + 4);
  union { unsigned short u[8]; short8 v; } o;
#pragma unroll
  for (int e = 0; e < 4; ++e) {
    o.u[e] = f2bf(a[e]);
    o.u[4 + e] = f2bf(b[e]);
  }
  *(short8*)(dst + idx) = o.v;
}

// ---------------------------------------------------------------------------
extern "C" void kernel_launch(void* const* d_in, const int* in_sizes, int n_in,
                              void* d_out, int out_size, void* d_ws,
                              size_t ws_size, hipStream_t stream) {
  const float* querys = (const float*)d_in[0];
  const float* keys = (const float*)d_in[1];
  const float* values = (const float*)d_in[2];
  const unsigned char* mask = (const unsigned char*)d_in[3];
  const float* Wq = (const float*)d_in[4];
  const float* bq = (const float*)d_in[5];
  const float* Wk = (const float*)d_in[6];
  const float* bk = (const float*)d_in[7];
  const float* Wv = (const float*)d_in[8];
  const float* bv = (const float*)d_in[9];
  const float* Wo = (const float*)d_in[10];
  const float* bo = (const float*)d_in[11];
  float* out = (float*)d_out;

  char* ws = (char*)d_ws;
  unsigned short* qb  = (unsigned short*)(ws + 0);          // 16 MB
  unsigned short* kb  = (unsigned short*)(ws + 16777216);   // 16 MB
  unsigned short* vb  = (unsigned short*)(ws + 33554432);   // 16 MB
  unsigned short* wqb = (unsigned short*)(ws + 50331648);   // 2 MB
  unsigned short* wkb = (unsigned short*)(ws + 52428800);   // 2 MB
  unsigned short* wvb = (unsigned short*)(ws + 54525952);   // 2 MB
  unsigned short* wob = (unsigned short*)(ws + 56623104);   // 2 MB
  unsigned short* Qf  = (unsigned short*)(ws + 58720256);   // 16 MB
  unsigned short* Kf  = (unsigned short*)(ws + 75497472);   // 16 MB
  unsigned short* Vf  = (unsigned short*)(ws + 92274688);   // 16 MB
  // kb/vb are dead after proj_gemm -> reuse for part (8.52MB) and Sx (0.66MB)
  float* part         = (float*)(ws + 16777216);
  unsigned short* Sx  = (unsigned short*)(ws + 33554432);
  unsigned short* out2 = qb;  // qb dead after proj_gemm; reuse as out2

  convert_all<<<dim3(4096, 7), 256, 0, stream>>>(querys, keys, values, Wq, Wk,
                                                 Wv, Wo, qb, kb, vb, wqb, wkb,
                                                 wvb, wob);
  proj_gemm<<<dim3(64, 8, 3), 256, 0, stream>>>(
      (const short*)qb, (const short*)kb, (const short*)vb, (const short*)wqb,
      (const short*)wkb, (const short*)wvb, bq, bk, bv, Qf, Kf, Vf, mask);
  s_partial<<<dim3(64, 8), 256, 0, stream>>>(Kf, Vf, part);
  s_reduce<<<dim3(64, 4), 256, 0, stream>>>(part, Sx);
  out_gemm<<<dim3(16, 64), 256, 0, stream>>>(Qf, Sx, out2);
  final_gemm<<<dim3(64, 8), 256, 0, stream>>>((const short*)out2,
                                              (const short*)wob, bo, out);
}

// Round 7
// 292.272 us; speedup vs baseline: 1.3812x; 1.0285x over previous
//
#include <hip/hip_runtime.h>
#include <cstdint>
#include <cstddef>

// ---------------------------------------------------------------------------
// RecurrentCrossAttentionLayer (linear attention, ELU feature map)
// B=4, L=2048, D_MODEL=1024, H=16, HD=64.
// Pipeline: convert->bf16; QKV proj GEMMs (MFMA, fused featuremap epilogue);
// S_ext = [V|1]^T K via MFMA (s_state, replaces VALU s_partial+s_reduce);
// O=Q S^T (+denom col) MFMA; final GEMM Wo.
// R6 change: s_state MFMA kernel (TN gemm w/ strided u16 frag reads; ones-row
// const frag produces Z in row 64, zeros rows 65-79). convert grid flattened.
// ---------------------------------------------------------------------------

typedef __attribute__((ext_vector_type(8))) short short8;
typedef __attribute__((ext_vector_type(4))) float f32x4;

#define EPS_F 1e-6f

__device__ __forceinline__ float bf2f(short u) {
  union { unsigned int i; float f; } c;
  c.i = ((unsigned int)(unsigned short)u) << 16;
  return c.f;
}
__device__ __forceinline__ unsigned short f2bf(float f) {
  union { float f; unsigned int i; } c;
  c.f = f;
  return (unsigned short)((c.i + 0x7fffu + ((c.i >> 16) & 1u)) >> 16);
}

typedef __attribute__((address_space(1))) const unsigned int gu32;
typedef __attribute__((address_space(3))) unsigned int lu32;

__device__ __forceinline__ void gload_lds16(const void* g, void* l) {
  __builtin_amdgcn_global_load_lds((gu32*)g, (lu32*)l, 16, 0, 0);
}

// ---------------------------------------------------------------------------
// 128x128 bf16 NT GEMM mainloop, K=1024, BK=64, 4 waves (64x64 quadrant each).
// LDS rows are 128B (64 bf16). XOR swizzle: LDS slot s of row r holds global
// 16B chunk (s ^ (r&7)); reader XORs the same way (involution, rule #21).
// ---------------------------------------------------------------------------
__device__ __forceinline__ void gemm_mainloop(const char* Ab, const char* Bb,
                                              char* AsB, char* BsB,
                                              int tm, int tn, f32x4 acc[4][4]) {
  const int t = threadIdx.x;
  const int l = t & 63;
  const int w = t >> 6;
  const int srow = l >> 3, sslot = l & 7;
  const int sso16 = ((sslot ^ srow) << 4);        // pre-swizzled source chunk
  const int rd0 = ((l & 15) << 7) | ((((l >> 4) + 0) ^ (l & 7)) << 4);
  const int rd1 = ((l & 15) << 7) | ((((l >> 4) + 4) ^ (l & 7)) << 4);
  const int wr = (w >> 1) << 6;
  const int wc = (w & 1) << 6;

#pragma unroll
  for (int i = 0; i < 4; ++i)
#pragma unroll
    for (int j = 0; j < 4; ++j) acc[i][j] = f32x4{0.f, 0.f, 0.f, 0.f};

  const char* Ag = Ab + (size_t)tm * 2048;  // row stride = 1024*2B
  const char* Bg = Bb + (size_t)tn * 2048;

  for (int kt = 0; kt < 16; ++kt) {
    __syncthreads();  // protect LDS from overwrite
    const int kofs = kt << 7;  // 64 bf16 = 128B per K-tile
#pragma unroll
    for (int i = 0; i < 4; ++i) {
      const int rr = (((w << 2) + i) << 3) + srow;  // 0..127
      gload_lds16(Ag + (size_t)rr * 2048 + kofs + sso16,
                  AsB + rr * 128 + (sslot << 4));
      gload_lds16(Bg + (size_t)rr * 2048 + kofs + sso16,
                  BsB + rr * 128 + (sslot << 4));
    }
    __syncthreads();  // compiler drains vmcnt(0) here
#pragma unroll
    for (int kk = 0; kk < 2; ++kk) {
      const int rdo = kk ? rd1 : rd0;
      short8 a[4], b[4];
#pragma unroll
      for (int i = 0; i < 4; ++i)
        a[i] = *(const short8*)(AsB + ((wr + i * 16) << 7) + rdo);
#pragma unroll
      for (int j = 0; j < 4; ++j)
        b[j] = *(const short8*)(BsB + ((wc + j * 16) << 7) + rdo);
#pragma unroll
      for (int i = 0; i < 4; ++i)
#pragma unroll
        for (int j = 0; j < 4; ++j)
          acc[i][j] = __builtin_amdgcn_mfma_f32_16x16x32_bf16(a[i], b[j],
                                                              acc[i][j], 0, 0, 0);
    }
  }
}

// ---------------------------------------------------------------------------
// QKV projection GEMMs (blockIdx.z = 0/1/2 -> q/k/v), fused feature-map
// epilogue, head-split output [B*H, L, 64] bf16.
// ---------------------------------------------------------------------------
__global__ __launch_bounds__(256) void proj_gemm(
    const short* __restrict__ qb, const short* __restrict__ kb,
    const short* __restrict__ vb, const short* __restrict__ Wq,
    const short* __restrict__ Wk, const short* __restrict__ Wv,
    const float* __restrict__ bq, const float* __restrict__ bk,
    const float* __restrict__ bv, unsigned short* __restrict__ Qf,
    unsigned short* __restrict__ Kf, unsigned short* __restrict__ Vf,
    const unsigned char* __restrict__ mask) {
  __shared__ char As[16384], Bs[16384];
  const int mode = blockIdx.z;
  const short* A = mode == 0 ? qb : (mode == 1 ? kb : vb);
  const short* B = mode == 0 ? Wq : (mode == 1 ? Wk : Wv);
  const float* bias = mode == 0 ? bq : (mode == 1 ? bk : bv);
  unsigned short* O = mode == 0 ? Qf : (mode == 1 ? Kf : Vf);
  const int tm = blockIdx.x << 7, tn = blockIdx.y << 7;
  f32x4 acc[4][4];
  gemm_mainloop((const char*)A, (const char*)B, As, Bs, tm, tn, acc);

  const int l = threadIdx.x & 63, w = threadIdx.x >> 6;
  const int wr = (w >> 1) << 6, wc = (w & 1) << 6;
  const int lr = (l >> 4) << 2, lc = l & 15;
#pragma unroll
  for (int i = 0; i < 4; ++i) {
#pragma unroll
    for (int r = 0; r < 4; ++r) {
      const int row = tm + wr + i * 16 + lr + r;  // 0..8191 = b*2048+s
      const bool msk = (mode == 1) && (mask[row] != 0);
      const int b = row >> 11, s = row & 2047;
#pragma unroll
      for (int j = 0; j < 4; ++j) {
        const int col = tn + wc + j * 16 + lc;  // 0..1023 = h*64+d
        float v = acc[i][j][r] + bias[col];
        if (mode == 0) {
          v *= 0.125f;                       // HEAD_DIM^-0.5
          v = (v > 0.f) ? (v + 1.f) : __expf(v);  // elu+1
        } else if (mode == 1) {
          v = (v > 0.f) ? (v + 1.f) : __expf(v);
          if (msk) v = 0.f;
        }
        const int h = col >> 6, d = col & 63;
        O[((size_t)(b * 16 + h) * 2048 + s) * 64 + d] = f2bf(v);
      }
    }
  }
}

// ---------------------------------------------------------------------------
// Final GEMM: out = out2 @ Wo^T + bo, fp32 output.
// ---------------------------------------------------------------------------
__global__ __launch_bounds__(256) void final_gemm(const short* __restrict__ A,
                                                  const short* __restrict__ Wo,
                                                  const float* __restrict__ bo,
                                                  float* __restrict__ out) {
  __shared__ char As[16384], Bs[16384];
  const int tm = blockIdx.x << 7, tn = blockIdx.y << 7;
  f32x4 acc[4][4];
  gemm_mainloop((const char*)A, (const char*)Wo, As, Bs, tm, tn, acc);
  const int l = threadIdx.x & 63, w = threadIdx.x >> 6;
  const int wr = (w >> 1) << 6, wc = (w & 1) << 6;
  const int lr = (l >> 4) << 2, lc = l & 15;
#pragma unroll
  for (int i = 0; i < 4; ++i)
#pragma unroll
    for (int r = 0; r < 4; ++r) {
      const int row = tm + wr + i * 16 + lr + r;
#pragma unroll
      for (int j = 0; j < 4; ++j) {
        const int col = tn + wc + j * 16 + lc;
        out[(size_t)row * 1024 + col] = acc[i][j][r] + bo[col];
      }
    }
}

// ---------------------------------------------------------------------------
// S_ext = [V | ones]^T @ K per bh, via MFMA (TN: both operands s-major).
// One block per bh; 4 waves split s (2048) into 512 each; 8 chunks of 256 s
// staged in LDS; A/B frags read with strided ds_read_u16 (4-way conflict ok).
// A-frag tile mi=4 is the CONSTANT ones-row frag -> acc row 64 = Z,
// rows 65..79 = 0 automatically. Cross-wave f32 reduce in LDS, bf16 out.
// Output: Sext[bh][80][64] bf16.
// ---------------------------------------------------------------------------
__global__ __launch_bounds__(256) void s_state(
    const unsigned short* __restrict__ Kf, const unsigned short* __restrict__ Vf,
    unsigned short* __restrict__ Sext) {
  __shared__ char sh[65536];  // [0,32K): K [256][64]; [32K,64K): V [256][64]
  unsigned short* Ks = (unsigned short*)sh;
  unsigned short* Vs = (unsigned short*)(sh + 32768);
  float* red = (float*)sh;  // reduction buffer [5120] (reused after compute)
  const int bh = blockIdx.x;
  const int t = threadIdx.x, l = t & 63, w = t >> 6;
  const unsigned short* Kb = Kf + (size_t)bh * 131072;  // 2048*64
  const unsigned short* Vb = Vf + (size_t)bh * 131072;

  f32x4 acc[5][4];
#pragma unroll
  for (int i = 0; i < 5; ++i)
#pragma unroll
    for (int j = 0; j < 4; ++j) acc[i][j] = f32x4{0.f, 0.f, 0.f, 0.f};

  // constant ones-row A-frag: Vaug[s][64 + (l&15)] = (l&15)==0 ? 1.0 : 0.0
  const short onebf = ((l & 15) == 0) ? (short)0x3F80 : (short)0;
  short8 a4;
#pragma unroll
  for (int e = 0; e < 8; ++e) a4[e] = onebf;

  for (int ch = 0; ch < 8; ++ch) {
    __syncthreads();  // protect LDS from overwrite
    const size_t gb = (size_t)ch * 16384;  // 256*64 elems
#pragma unroll
    for (int i = 0; i < 8; ++i) {
      const int eo = (i * 256 + t) * 8;  // bf16 elem offset; dest lane-linear
      gload_lds16(Kb + gb + eo, (char*)Ks + (size_t)eo * 2);
      gload_lds16(Vb + gb + eo, (char*)Vs + (size_t)eo * 2);
    }
    __syncthreads();  // drains vmcnt before reads
#pragma unroll
    for (int st = 0; st < 2; ++st) {
      // this lane's k-group base: s_local = wave*64 + st*32 + (l>>4)*8 + e
      const int sb = (w << 6) + (st << 5) + ((l >> 4) << 3);
      short8 b[4], a[4];
#pragma unroll
      for (int dj = 0; dj < 4; ++dj)
#pragma unroll
        for (int e = 0; e < 8; ++e)
          b[dj][e] = (short)Ks[(sb + e) * 64 + dj * 16 + (l & 15)];
#pragma unroll
      for (int mi = 0; mi < 4; ++mi)
#pragma unroll
        for (int e = 0; e < 8; ++e)
          a[mi][e] = (short)Vs[(sb + e) * 64 + mi * 16 + (l & 15)];
#pragma unroll
      for (int mi = 0; mi < 4; ++mi)
#pragma unroll
        for (int dj = 0; dj < 4; ++dj)
          acc[mi][dj] = __builtin_amdgcn_mfma_f32_16x16x32_bf16(
              a[mi], b[dj], acc[mi][dj], 0, 0, 0);
#pragma unroll
      for (int dj = 0; dj < 4; ++dj)
        acc[4][dj] = __builtin_amdgcn_mfma_f32_16x16x32_bf16(
            a4, b[dj], acc[4][dj], 0, 0, 0);
    }
  }

  __syncthreads();  // all compute done; LDS now reusable as red[]
  const int lr = (l >> 4) << 2, lc = l & 15;
  for (int wv = 0; wv < 4; ++wv) {
    if (w == wv) {
#pragma unroll
      for (int mi = 0; mi < 5; ++mi)
#pragma unroll
        for (int dj = 0; dj < 4; ++dj)
#pragma unroll
          for (int r = 0; r < 4; ++r) {
            const int idx = (mi * 16 + lr + r) * 64 + dj * 16 + lc;
            if (wv == 0) red[idx] = acc[mi][dj][r];
            else         red[idx] += acc[mi][dj][r];
          }
    }
    __syncthreads();
  }
  unsigned short* So = Sext + (size_t)bh * 5120;
#pragma unroll
  for (int i = 0; i < 20; ++i) So[i * 256 + t] = f2bf(red[i * 256 + t]);
}

// ---------------------------------------------------------------------------
// O = Q @ S_ext^T per (bh, 128-row q tile); col 64 = denominator Q.Z.
// Writes normalized out2 bf16 [B, L, 1024].
// ---------------------------------------------------------------------------
__global__ __launch_bounds__(256) void out_gemm(const unsigned short* __restrict__ Qf,
                                                const unsigned short* __restrict__ Sext,
                                                unsigned short* __restrict__ out2) {
  __shared__ char Qs[16384], Ss[10240];
  const int qt = blockIdx.x, bh = blockIdx.y;
  const int t = threadIdx.x, l = t & 63, w = t >> 6;
  const int srow = l >> 3, sslot = l & 7;
  const int sso16 = ((sslot ^ srow) << 4);
  const char* Qg = (const char*)(Qf + ((size_t)bh * 2048 + qt * 128) * 64);
  const char* Sg = (const char*)(Sext + (size_t)bh * 5120);
  for (int i = w; i < 16; i += 4) {
    const int rr = (i << 3) + srow;
    gload_lds16(Qg + (size_t)rr * 128 + sso16, Qs + rr * 128 + (sslot << 4));
  }
  for (int i = w; i < 10; i += 4) {
    const int rr = (i << 3) + srow;
    gload_lds16(Sg + (size_t)rr * 128 + sso16, Ss + rr * 128 + (sslot << 4));
  }
  __syncthreads();
  const int rd0 = ((l & 15) << 7) | ((((l >> 4) + 0) ^ (l & 7)) << 4);
  const int rd1 = ((l & 15) << 7) | ((((l >> 4) + 4) ^ (l & 7)) << 4);
  f32x4 acc[2][5];
#pragma unroll
  for (int i = 0; i < 2; ++i)
#pragma unroll
    for (int j = 0; j < 5; ++j) acc[i][j] = f32x4{0.f, 0.f, 0.f, 0.f};
#pragma unroll
  for (int kk = 0; kk < 2; ++kk) {
    const int rdo = kk ? rd1 : rd0;
    short8 a[2], b[5];
#pragma unroll
    for (int i = 0; i < 2; ++i)
      a[i] = *(const short8*)(Qs + ((w * 32 + i * 16) << 7) + rdo);
#pragma unroll
    for (int j = 0; j < 5; ++j)
      b[j] = *(const short8*)(Ss + ((j * 16) << 7) + rdo);
#pragma unroll
    for (int i = 0; i < 2; ++i)
#pragma unroll
      for (int j = 0; j < 5; ++j)
        acc[i][j] = __builtin_amdgcn_mfma_f32_16x16x32_bf16(a[i], b[j],
                                                            acc[i][j], 0, 0, 0);
  }
  const int b_ = bh >> 4, h = bh & 15;
#pragma unroll
  for (int i = 0; i < 2; ++i) {
#pragma unroll
    for (int r = 0; r < 4; ++r) {
      const float dv = __shfl(acc[i][4][r], (l & 48));  // col 64 holder
      const float qz = 1.f / (dv + EPS_F);
      const int q = qt * 128 + w * 32 + i * 16 + ((l >> 4) << 2) + r;
      unsigned short* po = out2 + ((size_t)b_ * 2048 + q) * 1024 + h * 64;
#pragma unroll
      for (int j = 0; j < 4; ++j) po[j * 16 + (l & 15)] = f2bf(acc[i][j][r] * qz);
    }
  }
}

// ---------------------------------------------------------------------------
// fp32 -> bf16 conversion for 3 big inputs + 4 weight matrices.
// 1D flattened grid: segs 0-2 get 4096 blocks each, segs 3-6 get 512 each.
// ---------------------------------------------------------------------------
__global__ __launch_bounds__(256) void convert_all(
    const float* __restrict__ s0, const float* __restrict__ s1,
    const float* __restrict__ s2, const float* __restrict__ s3,
    const float* __restrict__ s4, const float* __restrict__ s5,
    const float* __restrict__ s6, unsigned short* __restrict__ d0,
    unsigned short* __restrict__ d1, unsigned short* __restrict__ d2,
    unsigned short* __restrict__ d3, unsigned short* __restrict__ d4,
    unsigned short* __restrict__ d5, unsigned short* __restrict__ d6) {
  const int x = blockIdx.x;
  int seg, blk;
  if (x < 12288) { seg = x >> 12; blk = x & 4095; }
  else           { seg = 3 + ((x - 12288) >> 9); blk = (x - 12288) & 511; }
  const float* src;
  unsigned short* dst;
  switch (seg) {
    case 0: src = s0; dst = d0; break;
    case 1: src = s1; dst = d1; break;
    case 2: src = s2; dst = d2; break;
    case 3: src = s3; dst = d3; break;
    case 4: src = s4; dst = d4; break;
    case 5: src = s5; dst = d5; break;
    default: src = s6; dst = d6; break;
  }
  const int idx = (blk * 256 + threadIdx.x) * 8;
  const f32x4 a = *(const f32x4*)(src + idx);
  const f32x4 b = *(const f32x4*)(src + idx + 4);
  union { unsigned short u[8]; short8 v; } o;
#pragma unroll
  for (int e = 0; e < 4; ++e) {
    o.u[e] = f2bf(a[e]);
    o.u[4 + e] = f2bf(b[e]);
  }
  *(short8*)(dst + idx) = o.v;
}

// ---------------------------------------------------------------------------
extern "C" void kernel_launch(void* const* d_in, const int* in_sizes, int n_in,
                              void* d_out, int out_size, void* d_ws,
                              size_t ws_size, hipStream_t stream) {
  const float* querys = (const float*)d_in[0];
  const float* keys = (const float*)d_in[1];
  const float* values = (const float*)d_in[2];
  const unsigned char* mask = (const unsigned char*)d_in[3];
  const float* Wq = (const float*)d_in[4];
  const float* bq = (const float*)d_in[5];
  const float* Wk = (const float*)d_in[6];
  const float* bk = (const float*)d_in[7];
  const float* Wv = (const float*)d_in[8];
  const float* bv = (const float*)d_in[9];
  const float* Wo = (const float*)d_in[10];
  const float* bo = (const float*)d_in[11];
  float* out = (float*)d_out;

  char* ws = (char*)d_ws;
  unsigned short* qb  = (unsigned short*)(ws + 0);          // 16 MB
  unsigned short* kb  = (unsigned short*)(ws + 16777216);   // 16 MB
  unsigned short* vb  = (unsigned short*)(ws + 33554432);   // 16 MB
  unsigned short* wqb = (unsigned short*)(ws + 50331648);   // 2 MB
  unsigned short* wkb = (unsigned short*)(ws + 52428800);   // 2 MB
  unsigned short* wvb = (unsigned short*)(ws + 54525952);   // 2 MB
  unsigned short* wob = (unsigned short*)(ws + 56623104);   // 2 MB
  unsigned short* Qf  = (unsigned short*)(ws + 58720256);   // 16 MB
  unsigned short* Kf  = (unsigned short*)(ws + 75497472);   // 16 MB
  unsigned short* Vf  = (unsigned short*)(ws + 92274688);   // 16 MB
  // kb dead after proj_gemm -> reuse for Sx (0.66 MB)
  unsigned short* Sx  = (unsigned short*)(ws + 16777216);
  unsigned short* out2 = qb;  // qb dead after proj_gemm; reuse as out2

  convert_all<<<dim3(14336), 256, 0, stream>>>(querys, keys, values, Wq, Wk,
                                               Wv, Wo, qb, kb, vb, wqb, wkb,
                                               wvb, wob);
  proj_gemm<<<dim3(64, 8, 3), 256, 0, stream>>>(
      (const short*)qb, (const short*)kb, (const short*)vb, (const short*)wqb,
      (const short*)wkb, (const short*)wvb, bq, bk, bv, Qf, Kf, Vf, mask);
  s_state<<<dim3(64), 256, 0, stream>>>(Kf, Vf, Sx);
  out_gemm<<<dim3(16, 64), 256, 0, stream>>>(Qf, Sx, out2);
  final_gemm<<<dim3(64, 8), 256, 0, stream>>>((const short*)out2,
                                              (const short*)wob, bo, out);
}